// Round 23
// baseline (158.209 us; speedup 1.0000x reference)
//
#include <hip/hip_runtime.h>
#include <hip/hip_bf16.h>

typedef __attribute__((ext_vector_type(8))) short short8;
typedef __attribute__((ext_vector_type(4))) short short4v;
typedef __attribute__((ext_vector_type(4))) float f32x4;
typedef __attribute__((ext_vector_type(2))) unsigned uint2v;

#define BB 2
#define LL 2048
#define DD 1024
#define HH 16
#define DHH 64
#define KK 1024
#define NITEMS 2048
// 0.125 (1/sqrt(64)) * log2(e): folded into Q at the QKV epilogue
#define SCL 0.18033688011112042f
#define EXP2(x) __builtin_amdgcn_exp2f(x)

__device__ __forceinline__ void gload_lds16(const void* g, void* l) {
  __builtin_amdgcn_global_load_lds((const __attribute__((address_space(1))) void*)g,
                                   (__attribute__((address_space(3))) void*)l,
                                   16, 0, 0);
}

__device__ __forceinline__ unsigned short f2b(float x) {
  __hip_bfloat16 h = __float2bfloat16(x);
  return *reinterpret_cast<unsigned short*>(&h);
}

// HW packed f32->bf16 (RNE): one VALU inst vs ~5 for __float2bfloat16.
__device__ __forceinline__ unsigned cvtpk(float lo, float hi) {
  unsigned r;
  asm("v_cvt_pk_bf16_f32 %0, %1, %2" : "=v"(r) : "v"(lo), "v"(hi));
  return r;
}

// fused fp32 -> bf16 convert for x, w_in, w_out (one launch); also zeroes
// the work-stealing counter each launch (stream-ordered before attn_fwd).
#define NX8  ((BB * LL * DD) / 8)      // 524288
#define NWI8 ((3 * DD * DD) / 8)       // 393216
#define NWO8 ((DD * DD) / 8)           // 131072
__global__ void cvt_all(const float* __restrict__ x,
                        const float* __restrict__ w_in,
                        const float* __restrict__ w_out,
                        __hip_bfloat16* __restrict__ xb,
                        __hip_bfloat16* __restrict__ w_inb,
                        __hip_bfloat16* __restrict__ w_outb,
                        unsigned* __restrict__ wq) {
  int i = blockIdx.x * blockDim.x + threadIdx.x;
  if (i == 0) *wq = 0u;
  const float* src;
  __hip_bfloat16* dst;
  int j;
  if (i < NX8)              { src = x;     dst = xb;     j = i; }
  else if (i < NX8 + NWI8)  { src = w_in;  dst = w_inb;  j = i - NX8; }
  else                      { src = w_out; dst = w_outb; j = i - NX8 - NWI8; }
  const f32x4 a = ((const f32x4*)src)[j * 2];
  const f32x4 b = ((const f32x4*)src)[j * 2 + 1];
  short8 o;
#pragma unroll
  for (int k = 0; k < 4; ++k) o[k] = (short)f2b(a[k]);
#pragma unroll
  for (int k = 0; k < 4; ++k) o[4 + k] = (short)f2b(b[k]);
  ((short8*)dst)[j] = o;
}

// C = A @ B^T (+bias). A: MxK bf16 row-major, B: NxK bf16 row-major. K=1024.
// BK=64 (r19-validated: 16 K-steps, 32 MFMA per barrier-pair).
template<bool QKV>
__global__ void gemm_bt(const __hip_bfloat16* __restrict__ A,
                        const __hip_bfloat16* __restrict__ Bm,
                        const float* __restrict__ bias,
                        __hip_bfloat16* __restrict__ Cq,
                        __hip_bfloat16* __restrict__ Ck,
                        __hip_bfloat16* __restrict__ Cv,
                        float* __restrict__ Cd,
                        int N, int nbn) {
  __shared__ __align__(16) char As[16384];   // [128 rows][128B], swizzled
  __shared__ __align__(16) char Bs[16384];
  const int tid = threadIdx.x;
  const int lane = tid & 63, wid = tid >> 6;
  const int l15 = lane & 15, lhi = lane >> 4;
  const int wm = wid >> 1, wn = wid & 1;
  const int bn = blockIdx.x % nbn, bm = blockIdx.x / nbn;
  const int m0 = bm * 128, n0 = bn * 128;

  f32x4 acc[4][4] = {};

  for (int kt = 0; kt < KK / 64; ++kt) {
    const int k0 = kt * 64;
    __syncthreads();
    // stage A+B tiles: chunk c: row = c>>3, byte = ((c&7)*16) ^ ((row&7)<<4)
#pragma unroll
    for (int j = 0; j < 4; ++j) {
      int c = wid * 256 + j * 64 + lane;
      int row = c >> 3;
      int ab = ((c & 7) * 16) ^ ((row & 7) << 4);
      gload_lds16(A + (size_t)(m0 + row) * KK + k0 + (ab >> 1),
                  As + wid * 4096 + j * 1024);
    }
#pragma unroll
    for (int j = 0; j < 4; ++j) {
      int c = wid * 256 + j * 64 + lane;
      int row = c >> 3;
      int ab = ((c & 7) * 16) ^ ((row & 7) << 4);
      gload_lds16(Bm + (size_t)(n0 + row) * KK + k0 + (ab >> 1),
                  Bs + wid * 4096 + j * 1024);
    }
    __syncthreads();

#pragma unroll
    for (int kk = 0; kk < 2; ++kk) {
      short8 af[4], bf[4];
#pragma unroll
      for (int mf = 0; mf < 4; ++mf) {
        int row = wm * 64 + mf * 16 + l15;
        int byt = (kk * 64 + lhi * 16) ^ ((row & 7) << 4);
        af[mf] = *(const short8*)(As + row * 128 + byt);
      }
#pragma unroll
      for (int nf = 0; nf < 4; ++nf) {
        int row = wn * 64 + nf * 16 + l15;
        int byt = (kk * 64 + lhi * 16) ^ ((row & 7) << 4);
        bf[nf] = *(const short8*)(Bs + row * 128 + byt);
      }
#pragma unroll
      for (int mf = 0; mf < 4; ++mf)
#pragma unroll
        for (int nf = 0; nf < 4; ++nf)
          acc[mf][nf] = __builtin_amdgcn_mfma_f32_16x16x32_bf16(af[mf], bf[nf],
                                                                acc[mf][nf], 0, 0, 0);
    }
  }

  // epilogue: C/D layout col=lane&15, row=(lane>>4)*4+reg
#pragma unroll
  for (int mf = 0; mf < 4; ++mf) {
#pragma unroll
    for (int nf = 0; nf < 4; ++nf) {
      const int n = n0 + wn * 64 + nf * 16 + l15;
      if constexpr (QKV) {
        const int sect = n >> 10;          // 0=q 1=k 2=v
        const int nn = n & 1023;
        const int h = nn >> 6, dh = nn & 63;
        const float bv = bias[n];
        const int m_base = m0 + wm * 64 + mf * 16 + lhi * 4;   // +r, same 2k page
        const int b = m_base >> 11, ml = m_base & 2047;
        if (sect == 2) {
          // V transposed: [b*H+h][dh][l]; 4 r-values are l-contiguous -> 8B store
          short4v v;
#pragma unroll
          for (int r = 0; r < 4; ++r) v[r] = (short)f2b(acc[mf][nf][r] + bv);
          *(short4v*)&Cv[(((size_t)(b * HH + h)) * DHH + dh) * LL + ml] = v;
        } else {
          __hip_bfloat16* dst = (sect == 0) ? Cq : Ck;
          const float scl = (sect == 0) ? SCL : 1.0f;   // fold softmax scale into Q
#pragma unroll
          for (int r = 0; r < 4; ++r)
            dst[(((size_t)(b * HH + h)) * LL + ml + r) * DHH + dh] =
                __float2bfloat16((acc[mf][nf][r] + bv) * scl);
        }
      } else {
#pragma unroll
        for (int r = 0; r < 4; ++r) {
          const int m = m0 + wm * 64 + mf * 16 + lhi * 4 + r;
          Cd[(size_t)m * N + n] = acc[mf][nf][r];
        }
      }
    }
  }
}

// Flash attention, swapped-operand body (r18/r19, 74.6us) + PERSISTENT
// WORK-STEALING: 2048 resident blocks loop fetching strip-items from a
// global atomic counter (heavy strips first, light strips drain the tail).
// Fixes the r19 profile: grid == residency meant zero refill queue; light
// blocks retired early leaving ~2 heavy blocks/CU latency-exposed (occ 19%).
// Output is assignment-independent -> deterministic.
__global__ __launch_bounds__(128)
__attribute__((amdgpu_waves_per_eu(1, 4)))
void attn_fwd(
    const __hip_bfloat16* __restrict__ Q,
    const __hip_bfloat16* __restrict__ K,
    const __hip_bfloat16* __restrict__ VT,
    __hip_bfloat16* __restrict__ att,
    const int* __restrict__ maskp,
    unsigned* __restrict__ wq) {
  __shared__ __align__(16) char shm[8960];
  __shared__ int curidx;
  // loop phase:  Pbuf = shm[0..8192), per-wave [row32][128B], off^=((l15&7)<<4)
  // merge phase: Ob = shm[0..8704) as float[32][68]; Mb@8704; Lb@8832
  char* Pw = shm + (threadIdx.x >> 6) * 4096;
  float (*Ob)[68] = (float(*)[68])shm;
  float* Mb = (float*)(shm + 8704);
  float* Lb = (float*)(shm + 8832);
  const int tid = threadIdx.x;
  const int lane = tid & 63, wid = tid >> 6;
  const int l15 = lane & 15, lhi = lane >> 4;
  const int causal = *maskp;
  const int swz = (l15 & 7) << 4;

  for (;;) {
    if (tid == 0) curidx = (int)atomicAdd(wq, 1u);
    __syncthreads();                        // broadcast idx; also fences shm reuse
    const int idx = curidx;
    if (idx >= NITEMS) break;
    const int strip = 63 - (idx >> 5);      // heavy strips first in the queue
    const int bh = idx & 31;
    const int r0 = strip * 32;
    const __hip_bfloat16* Qg = Q + (size_t)bh * LL * DHH;
    const __hip_bfloat16* Kg = K + (size_t)bh * LL * DHH;
    const __hip_bfloat16* VTg = VT + (size_t)bh * DHH * LL;

    // Q fragments (B-operand; pre-scaled by SCL in the QKV epilogue)
    short8 aq[2][2];
#pragma unroll
    for (int mf = 0; mf < 2; ++mf)
#pragma unroll
      for (int ks = 0; ks < 2; ++ks)
        aq[mf][ks] = *(const short8*)(Qg + (size_t)(r0 + mf * 16 + l15) * DHH +
                                      ks * 32 + lhi * 8);

    f32x4 o[2][4] = {};
    float mrun[2] = {-1e30f, -1e30f};
    float lrun[2] = {0.0f, 0.0f};

    const int nt = causal ? ((r0 + 31) >> 6) + 1 : (LL / 64);
    const int hf = (nt + 1) >> 1;           // wave 0: [0,hf)  wave 1: [hf,nt)
    const int t0 = wid ? hf : 0;
    const int t1 = wid ? nt : hf;

    // stepped base pointers (advance once per tile; loads use imm offsets)
    const __hip_bfloat16* kb0 = Kg + (size_t)(t0 * 64 + l15) * DHH + lhi * 8;        // nf 0,1
    const __hip_bfloat16* kb2 = Kg + (size_t)(t0 * 64 + 32 + l15) * DHH + lhi * 8;   // nf 2,3
    const __hip_bfloat16* vp0 = VTg + (size_t)(l15) * LL + t0 * 64 + lhi * 8;
    const __hip_bfloat16* vp1 = VTg + (size_t)(16 + l15) * LL + t0 * 64 + lhi * 8;
    const __hip_bfloat16* vp2 = VTg + (size_t)(32 + l15) * LL + t0 * 64 + lhi * 8;
    const __hip_bfloat16* vp3 = VTg + (size_t)(48 + l15) * LL + t0 * 64 + lhi * 8;

    for (int t = t0; t < t1; ++t) {
      const int kv0 = t * 64;
      f32x4 s[2][4] = {};

      // K half 0 first (oldest in vmcnt queue), then ALL V loads: QK^T waits
      // only for K; V stays in flight under softmax.
      short8 kah[4];
      kah[0] = *(const short8*)(kb0);
      kah[1] = *(const short8*)(kb0 + 1024);
      kah[2] = *(const short8*)(kb2);
      kah[3] = *(const short8*)(kb2 + 1024);
      short8 bv[4][2];
      bv[0][0] = *(const short8*)(vp0);  bv[0][1] = *(const short8*)(vp0 + 32);
      bv[1][0] = *(const short8*)(vp1);  bv[1][1] = *(const short8*)(vp1 + 32);
      bv[2][0] = *(const short8*)(vp2);  bv[2][1] = *(const short8*)(vp2 + 32);
      bv[3][0] = *(const short8*)(vp3);  bv[3][1] = *(const short8*)(vp3 + 32);

      // swapped QK^T: s[mf][nf][r] = S[q = r0+mf*16+l15][kv = kv0+nf*16+lhi*4+r]
      __builtin_amdgcn_s_setprio(1);
#pragma unroll
      for (int nf = 0; nf < 4; ++nf) {
        s[0][nf] = __builtin_amdgcn_mfma_f32_16x16x32_bf16(kah[nf], aq[0][0], s[0][nf], 0, 0, 0);
        s[1][nf] = __builtin_amdgcn_mfma_f32_16x16x32_bf16(kah[nf], aq[1][0], s[1][nf], 0, 0, 0);
      }
      __builtin_amdgcn_s_setprio(0);
      // K half 1
      kah[0] = *(const short8*)(kb0 + 32);
      kah[1] = *(const short8*)(kb0 + 1024 + 32);
      kah[2] = *(const short8*)(kb2 + 32);
      kah[3] = *(const short8*)(kb2 + 1024 + 32);
      __builtin_amdgcn_s_setprio(1);
#pragma unroll
      for (int nf = 0; nf < 4; ++nf) {
        s[0][nf] = __builtin_amdgcn_mfma_f32_16x16x32_bf16(kah[nf], aq[0][1], s[0][nf], 0, 0, 0);
        s[1][nf] = __builtin_amdgcn_mfma_f32_16x16x32_bf16(kah[nf], aq[1][1], s[1][nf], 0, 0, 0);
      }
      __builtin_amdgcn_s_setprio(0);

      // advance base pointers to next tile
      kb0 += 4096; kb2 += 4096;
      vp0 += 64; vp1 += 64; vp2 += 64; vp3 += 64;

      const bool needmask = causal && (kv0 + 63 > r0);
#pragma unroll
      for (int mf = 0; mf < 2; ++mf) {
        const int q = r0 + mf * 16 + l15;
        // causal mask only (scale already folded into Q)
        if (needmask)
#pragma unroll
          for (int nf = 0; nf < 4; ++nf) {
            const int kvb = kv0 + nf * 16 + lhi * 4;
#pragma unroll
            for (int r = 0; r < 4; ++r)
              if (kvb + r > q) s[mf][nf][r] = -1e30f;
          }
        // row max: in-register over nf,r then 2 shfl over lhi
        f32x4 t4 = s[mf][0];
#pragma unroll
        for (int nf = 1; nf < 4; ++nf)
#pragma unroll
          for (int r = 0; r < 4; ++r) t4[r] = fmaxf(t4[r], s[mf][nf][r]);
        float pm = fmaxf(fmaxf(t4[0], t4[1]), fmaxf(t4[2], t4[3]));
        pm = fmaxf(pm, __shfl_xor(pm, 16, 64));
        pm = fmaxf(pm, __shfl_xor(pm, 32, 64));
        // defer-max: only rescale when the running max grew materially
        if (__any(pm > mrun[mf] + 8.0f)) {
          const float mnew = fmaxf(mrun[mf], pm);
          const float sc = EXP2(mrun[mf] - mnew);
          mrun[mf] = mnew;
          lrun[mf] *= sc;
#pragma unroll
          for (int nf = 0; nf < 4; ++nf)
#pragma unroll
            for (int r = 0; r < 4; ++r) o[mf][nf][r] *= sc;
        }
        float rs = 0.0f;
#pragma unroll
        for (int nf = 0; nf < 4; ++nf)
#pragma unroll
          for (int r = 0; r < 4; ++r) {
            float p = EXP2(s[mf][nf][r] - mrun[mf]);
            s[mf][nf][r] = p;
            rs += p;
          }
        rs += __shfl_xor(rs, 16, 64);
        rs += __shfl_xor(rs, 32, 64);
        lrun[mf] += rs;

        // P -> LDS: cvt_pk pairs + one ds_write_b64 per nf
        char* base = Pw + (mf * 16 + l15) * 128;
#pragma unroll
        for (int nf = 0; nf < 4; ++nf) {
          unsigned lo = cvtpk(s[mf][nf][0], s[mf][nf][1]);
          unsigned hi = cvtpk(s[mf][nf][2], s[mf][nf][3]);
          *(unsigned long long*)(base + ((nf * 32 + lhi * 8) ^ swz)) =
              (unsigned long long)lo | ((unsigned long long)hi << 32);
        }
      }

      // swapped PV: o[mf][nf][r] = O[q = r0+mf*16+l15][dh = nf*16+lhi*4+r]
      __builtin_amdgcn_s_setprio(1);
#pragma unroll
      for (int mf = 0; mf < 2; ++mf) {
        const char* base = Pw + (mf * 16 + l15) * 128;
        short8 ap0 = *(const short8*)(base + ((lhi * 16) ^ swz));
        short8 ap1 = *(const short8*)(base + ((64 + lhi * 16) ^ swz));
#pragma unroll
        for (int nf = 0; nf < 4; ++nf) {
          o[mf][nf] = __builtin_amdgcn_mfma_f32_16x16x32_bf16(bv[nf][0], ap0, o[mf][nf], 0, 0, 0);
          o[mf][nf] = __builtin_amdgcn_mfma_f32_16x16x32_bf16(bv[nf][1], ap1, o[mf][nf], 0, 0, 0);
        }
      }
      __builtin_amdgcn_s_setprio(0);
    }

    // merge the two kv-half partials (flash combine), then store.
    // Barrier REQUIRED before the dump: Ob overlays Pbuf.
    __syncthreads();
    if (wid == 1) {
#pragma unroll
      for (int mf = 0; mf < 2; ++mf) {
        const int row = mf * 16 + l15;
        if (lhi == 0) { Mb[row] = mrun[mf]; Lb[row] = lrun[mf]; }
#pragma unroll
        for (int nf = 0; nf < 4; ++nf)
          *(f32x4*)&Ob[row][nf * 16 + lhi * 4] = o[mf][nf];
      }
    }
    __syncthreads();
    if (wid == 0) {
      const int b_ = bh >> 4, h = bh & 15;
#pragma unroll
      for (int mf = 0; mf < 2; ++mf) {
        const int row = mf * 16 + l15;
        const float m1 = Mb[row], l1 = Lb[row];
        const float mt = fmaxf(mrun[mf], m1);
        const float sc0 = EXP2(mrun[mf] - mt);
        const float sc1 = EXP2(m1 - mt);
        const float inv = 1.0f / (lrun[mf] * sc0 + l1 * sc1);
        __hip_bfloat16* dst = att + ((size_t)(b_ * LL + r0 + row)) * DD + h * DHH;
#pragma unroll
        for (int nf = 0; nf < 4; ++nf) {
          f32x4 ov = *(const f32x4*)&Ob[row][nf * 16 + lhi * 4];
          float f0 = (o[mf][nf][0] * sc0 + ov[0] * sc1) * inv;
          float f1 = (o[mf][nf][1] * sc0 + ov[1] * sc1) * inv;
          float f2 = (o[mf][nf][2] * sc0 + ov[2] * sc1) * inv;
          float f3 = (o[mf][nf][3] * sc0 + ov[3] * sc1) * inv;
          uint2v pk;
          pk[0] = cvtpk(f0, f1);
          pk[1] = cvtpk(f2, f3);
          *(uint2v*)(dst + nf * 16 + lhi * 4) = pk;
        }
      }
    }
    // top-of-loop __syncthreads() fences Ob reads vs next item's Pbuf writes
  }
}

extern "C" void kernel_launch(void* const* d_in, const int* in_sizes, int n_in,
                              void* d_out, int out_size, void* d_ws, size_t ws_size,
                              hipStream_t stream) {
  const float* x     = (const float*)d_in[0];
  const float* w_in  = (const float*)d_in[1];
  const float* b_in  = (const float*)d_in[2];
  const float* w_out = (const float*)d_in[3];
  const int* mask    = (const int*)d_in[4];
  float* out = (float*)d_out;

  char* ws = (char*)d_ws;
  const size_t MiB = 1024u * 1024u;
  __hip_bfloat16* xb    = (__hip_bfloat16*)(ws);             // 8 MiB
  __hip_bfloat16* w_inb = (__hip_bfloat16*)(ws + 8 * MiB);   // 6 MiB
  __hip_bfloat16* w_outb= (__hip_bfloat16*)(ws + 14 * MiB);  // 2 MiB
  __hip_bfloat16* Qb    = (__hip_bfloat16*)(ws + 16 * MiB);  // 8 MiB
  __hip_bfloat16* Kb    = (__hip_bfloat16*)(ws + 24 * MiB);  // 8 MiB
  __hip_bfloat16* Vtb   = (__hip_bfloat16*)(ws + 32 * MiB);  // 8 MiB (transposed)
  __hip_bfloat16* att   = (__hip_bfloat16*)(ws + 40 * MiB);  // 8 MiB
  unsigned* wq          = (unsigned*)(ws + 48 * MiB);        // work-steal counter

  // fused conversions (also zeroes wq, stream-ordered before attn)
  cvt_all<<<dim3(4096), dim3(256), 0, stream>>>(x, w_in, w_out, xb, w_inb, w_outb, wq);

  gemm_bt<true><<<dim3(32 * 24), dim3(256), 0, stream>>>(
      xb, w_inb, b_in, Qb, Kb, Vtb, nullptr, 3072, 24);
  attn_fwd<<<dim3(2048), dim3(128), 0, stream>>>(Qb, Kb, Vtb, att, mask, wq);
  gemm_bt<false><<<dim3(32 * 8), dim3(256), 0, stream>>>(
      att, w_outb, nullptr, nullptr, nullptr, nullptr, out, 1024, 8);
}

// Round 24
// 129.850 us; speedup vs baseline: 1.2184x; 1.2184x over previous
//
#include <hip/hip_runtime.h>
#include <hip/hip_bf16.h>

typedef __attribute__((ext_vector_type(8))) short short8;
typedef __attribute__((ext_vector_type(4))) short short4v;
typedef __attribute__((ext_vector_type(4))) float f32x4;
typedef __attribute__((ext_vector_type(2))) unsigned uint2v;

#define BB 2
#define LL 2048
#define DD 1024
#define HH 16
#define DHH 64
#define KK 1024
// 0.125 (1/sqrt(64)) * log2(e): folded into Q at the QKV epilogue
#define SCL 0.18033688011112042f
#define EXP2(x) __builtin_amdgcn_exp2f(x)

__device__ __forceinline__ void gload_lds16(const void* g, void* l) {
  __builtin_amdgcn_global_load_lds((const __attribute__((address_space(1))) void*)g,
                                   (__attribute__((address_space(3))) void*)l,
                                   16, 0, 0);
}

__device__ __forceinline__ unsigned short f2b(float x) {
  __hip_bfloat16 h = __float2bfloat16(x);
  return *reinterpret_cast<unsigned short*>(&h);
}

// HW packed f32->bf16 (RNE): one VALU inst vs ~5 for __float2bfloat16.
__device__ __forceinline__ unsigned cvtpk(float lo, float hi) {
  unsigned r;
  asm("v_cvt_pk_bf16_f32 %0, %1, %2" : "=v"(r) : "v"(lo), "v"(hi));
  return r;
}

// fused fp32 -> bf16 convert for x, w_in, w_out (one launch)
#define NX8  ((BB * LL * DD) / 8)      // 524288
#define NWI8 ((3 * DD * DD) / 8)       // 393216
#define NWO8 ((DD * DD) / 8)           // 131072
__global__ void cvt_all(const float* __restrict__ x,
                        const float* __restrict__ w_in,
                        const float* __restrict__ w_out,
                        __hip_bfloat16* __restrict__ xb,
                        __hip_bfloat16* __restrict__ w_inb,
                        __hip_bfloat16* __restrict__ w_outb) {
  int i = blockIdx.x * blockDim.x + threadIdx.x;
  const float* src;
  __hip_bfloat16* dst;
  int j;
  if (i < NX8)              { src = x;     dst = xb;     j = i; }
  else if (i < NX8 + NWI8)  { src = w_in;  dst = w_inb;  j = i - NX8; }
  else                      { src = w_out; dst = w_outb; j = i - NX8 - NWI8; }
  const f32x4 a = ((const f32x4*)src)[j * 2];
  const f32x4 b = ((const f32x4*)src)[j * 2 + 1];
  short8 o;
#pragma unroll
  for (int k = 0; k < 4; ++k) o[k] = (short)f2b(a[k]);
#pragma unroll
  for (int k = 0; k < 4; ++k) o[4 + k] = (short)f2b(b[k]);
  ((short8*)dst)[j] = o;
}

// C = A @ B^T (+bias). A: MxK bf16 row-major, B: NxK bf16 row-major. K=1024.
// BK=64 (r19-validated: 16 K-steps, 32 MFMA per barrier-pair).
template<bool QKV>
__global__ void gemm_bt(const __hip_bfloat16* __restrict__ A,
                        const __hip_bfloat16* __restrict__ Bm,
                        const float* __restrict__ bias,
                        __hip_bfloat16* __restrict__ Cq,
                        __hip_bfloat16* __restrict__ Ck,
                        __hip_bfloat16* __restrict__ Cv,
                        float* __restrict__ Cd,
                        int N, int nbn) {
  __shared__ __align__(16) char As[16384];   // [128 rows][128B], swizzled
  __shared__ __align__(16) char Bs[16384];
  const int tid = threadIdx.x;
  const int lane = tid & 63, wid = tid >> 6;
  const int l15 = lane & 15, lhi = lane >> 4;
  const int wm = wid >> 1, wn = wid & 1;
  const int bn = blockIdx.x % nbn, bm = blockIdx.x / nbn;
  const int m0 = bm * 128, n0 = bn * 128;

  f32x4 acc[4][4] = {};

  for (int kt = 0; kt < KK / 64; ++kt) {
    const int k0 = kt * 64;
    __syncthreads();
    // stage A+B tiles: chunk c: row = c>>3, byte = ((c&7)*16) ^ ((row&7)<<4)
#pragma unroll
    for (int j = 0; j < 4; ++j) {
      int c = wid * 256 + j * 64 + lane;
      int row = c >> 3;
      int ab = ((c & 7) * 16) ^ ((row & 7) << 4);
      gload_lds16(A + (size_t)(m0 + row) * KK + k0 + (ab >> 1),
                  As + wid * 4096 + j * 1024);
    }
#pragma unroll
    for (int j = 0; j < 4; ++j) {
      int c = wid * 256 + j * 64 + lane;
      int row = c >> 3;
      int ab = ((c & 7) * 16) ^ ((row & 7) << 4);
      gload_lds16(Bm + (size_t)(n0 + row) * KK + k0 + (ab >> 1),
                  Bs + wid * 4096 + j * 1024);
    }
    __syncthreads();

#pragma unroll
    for (int kk = 0; kk < 2; ++kk) {
      short8 af[4], bf[4];
#pragma unroll
      for (int mf = 0; mf < 4; ++mf) {
        int row = wm * 64 + mf * 16 + l15;
        int byt = (kk * 64 + lhi * 16) ^ ((row & 7) << 4);
        af[mf] = *(const short8*)(As + row * 128 + byt);
      }
#pragma unroll
      for (int nf = 0; nf < 4; ++nf) {
        int row = wn * 64 + nf * 16 + l15;
        int byt = (kk * 64 + lhi * 16) ^ ((row & 7) << 4);
        bf[nf] = *(const short8*)(Bs + row * 128 + byt);
      }
#pragma unroll
      for (int mf = 0; mf < 4; ++mf)
#pragma unroll
        for (int nf = 0; nf < 4; ++nf)
          acc[mf][nf] = __builtin_amdgcn_mfma_f32_16x16x32_bf16(af[mf], bf[nf],
                                                                acc[mf][nf], 0, 0, 0);
    }
  }

  // epilogue: C/D layout col=lane&15, row=(lane>>4)*4+reg
#pragma unroll
  for (int mf = 0; mf < 4; ++mf) {
#pragma unroll
    for (int nf = 0; nf < 4; ++nf) {
      const int n = n0 + wn * 64 + nf * 16 + l15;
      if constexpr (QKV) {
        const int sect = n >> 10;          // 0=q 1=k 2=v
        const int nn = n & 1023;
        const int h = nn >> 6, dh = nn & 63;
        const float bv = bias[n];
        const int m_base = m0 + wm * 64 + mf * 16 + lhi * 4;   // +r, same 2k page
        const int b = m_base >> 11, ml = m_base & 2047;
        if (sect == 2) {
          // V transposed: [b*H+h][dh][l]; 4 r-values are l-contiguous -> 8B store
          short4v v;
#pragma unroll
          for (int r = 0; r < 4; ++r) v[r] = (short)f2b(acc[mf][nf][r] + bv);
          *(short4v*)&Cv[(((size_t)(b * HH + h)) * DHH + dh) * LL + ml] = v;
        } else {
          __hip_bfloat16* dst = (sect == 0) ? Cq : Ck;
          const float scl = (sect == 0) ? SCL : 1.0f;   // fold softmax scale into Q
#pragma unroll
          for (int r = 0; r < 4; ++r)
            dst[(((size_t)(b * HH + h)) * LL + ml + r) * DHH + dh] =
                __float2bfloat16((acc[mf][nf][r] + bv) * scl);
        }
      } else {
#pragma unroll
        for (int r = 0; r < 4; ++r) {
          const int m = m0 + wm * 64 + mf * 16 + lhi * 4 + r;
          Cd[(size_t)m * N + n] = acc[mf][nf][r];
        }
      }
    }
  }
}

// Flash attention, swapped-operand form (r18/r19 proven best: 74.6us):
// 2048 blocks x 2 waves; block = 32 q-rows; wave0 kv [0,hf), wave1 [hf,nt).
// strip = 63-(bid>>5) (descending, head pinned to XCD via bid&31 -- the
// static mapping preserves L2 locality; r23's dynamic queue broke it and
// FETCH went 12MB->130MB). QK^T as mfma(K,Q) -> softmax = 15 fmax + 2 shfl;
// PV as mfma(V^T,P); cvt_pk packing; stepped pointers.
__global__ __launch_bounds__(128)
__attribute__((amdgpu_waves_per_eu(1, 4)))
void attn_fwd(
    const __hip_bfloat16* __restrict__ Q,
    const __hip_bfloat16* __restrict__ K,
    const __hip_bfloat16* __restrict__ VT,
    __hip_bfloat16* __restrict__ att,
    const int* __restrict__ maskp) {
  __shared__ __align__(16) char shm[8960];
  // loop phase:  Pbuf = shm[0..8192), per-wave [row32][128B], off^=((l15&7)<<4)
  // merge phase: Ob = shm[0..8704) as float[32][68]; Mb@8704; Lb@8832
  char* Pw = shm + (threadIdx.x >> 6) * 4096;
  float (*Ob)[68] = (float(*)[68])shm;
  float* Mb = (float*)(shm + 8704);
  float* Lb = (float*)(shm + 8832);
  const int tid = threadIdx.x;
  const int lane = tid & 63, wid = tid >> 6;
  const int l15 = lane & 15, lhi = lane >> 4;
  const int bid = blockIdx.x;
  const int strip = 63 - (bid >> 5);        // heavy strips dispatched first
  const int bh = bid & 31;                  // head pinned to one XCD's L2
  const int causal = *maskp;
  const int r0 = strip * 32;
  const __hip_bfloat16* Qg = Q + (size_t)bh * LL * DHH;
  const __hip_bfloat16* Kg = K + (size_t)bh * LL * DHH;
  const __hip_bfloat16* VTg = VT + (size_t)bh * DHH * LL;
  const int swz = (l15 & 7) << 4;

  // Q fragments (B-operand; pre-scaled by SCL in the QKV epilogue)
  short8 aq[2][2];
#pragma unroll
  for (int mf = 0; mf < 2; ++mf)
#pragma unroll
    for (int ks = 0; ks < 2; ++ks)
      aq[mf][ks] = *(const short8*)(Qg + (size_t)(r0 + mf * 16 + l15) * DHH +
                                    ks * 32 + lhi * 8);

  f32x4 o[2][4] = {};
  float mrun[2] = {-1e30f, -1e30f};
  float lrun[2] = {0.0f, 0.0f};

  const int nt = causal ? ((r0 + 31) >> 6) + 1 : (LL / 64);
  const int hf = (nt + 1) >> 1;             // wave 0: [0,hf)  wave 1: [hf,nt)
  const int t0 = wid ? hf : 0;
  const int t1 = wid ? nt : hf;

  // stepped base pointers (advance once per tile; loads use imm offsets)
  const __hip_bfloat16* kb0 = Kg + (size_t)(t0 * 64 + l15) * DHH + lhi * 8;        // nf 0,1
  const __hip_bfloat16* kb2 = Kg + (size_t)(t0 * 64 + 32 + l15) * DHH + lhi * 8;   // nf 2,3
  const __hip_bfloat16* vp0 = VTg + (size_t)(l15) * LL + t0 * 64 + lhi * 8;
  const __hip_bfloat16* vp1 = VTg + (size_t)(16 + l15) * LL + t0 * 64 + lhi * 8;
  const __hip_bfloat16* vp2 = VTg + (size_t)(32 + l15) * LL + t0 * 64 + lhi * 8;
  const __hip_bfloat16* vp3 = VTg + (size_t)(48 + l15) * LL + t0 * 64 + lhi * 8;

  for (int t = t0; t < t1; ++t) {
    const int kv0 = t * 64;
    f32x4 s[2][4] = {};

    // K half 0 first (oldest in vmcnt queue), then ALL V loads: QK^T waits
    // only for K; V stays in flight under softmax.
    short8 kah[4];
    kah[0] = *(const short8*)(kb0);
    kah[1] = *(const short8*)(kb0 + 1024);
    kah[2] = *(const short8*)(kb2);
    kah[3] = *(const short8*)(kb2 + 1024);
    short8 bv[4][2];
    bv[0][0] = *(const short8*)(vp0);  bv[0][1] = *(const short8*)(vp0 + 32);
    bv[1][0] = *(const short8*)(vp1);  bv[1][1] = *(const short8*)(vp1 + 32);
    bv[2][0] = *(const short8*)(vp2);  bv[2][1] = *(const short8*)(vp2 + 32);
    bv[3][0] = *(const short8*)(vp3);  bv[3][1] = *(const short8*)(vp3 + 32);

    // swapped QK^T: s[mf][nf][r] = S[q = r0+mf*16+l15][kv = kv0+nf*16+lhi*4+r]
    __builtin_amdgcn_s_setprio(1);
#pragma unroll
    for (int nf = 0; nf < 4; ++nf) {
      s[0][nf] = __builtin_amdgcn_mfma_f32_16x16x32_bf16(kah[nf], aq[0][0], s[0][nf], 0, 0, 0);
      s[1][nf] = __builtin_amdgcn_mfma_f32_16x16x32_bf16(kah[nf], aq[1][0], s[1][nf], 0, 0, 0);
    }
    __builtin_amdgcn_s_setprio(0);
    // K half 1
    kah[0] = *(const short8*)(kb0 + 32);
    kah[1] = *(const short8*)(kb0 + 1024 + 32);
    kah[2] = *(const short8*)(kb2 + 32);
    kah[3] = *(const short8*)(kb2 + 1024 + 32);
    __builtin_amdgcn_s_setprio(1);
#pragma unroll
    for (int nf = 0; nf < 4; ++nf) {
      s[0][nf] = __builtin_amdgcn_mfma_f32_16x16x32_bf16(kah[nf], aq[0][1], s[0][nf], 0, 0, 0);
      s[1][nf] = __builtin_amdgcn_mfma_f32_16x16x32_bf16(kah[nf], aq[1][1], s[1][nf], 0, 0, 0);
    }
    __builtin_amdgcn_s_setprio(0);

    // advance base pointers to next tile
    kb0 += 4096; kb2 += 4096;
    vp0 += 64; vp1 += 64; vp2 += 64; vp3 += 64;

    const bool needmask = causal && (kv0 + 63 > r0);
#pragma unroll
    for (int mf = 0; mf < 2; ++mf) {
      const int q = r0 + mf * 16 + l15;
      // causal mask only (scale already folded into Q)
      if (needmask)
#pragma unroll
        for (int nf = 0; nf < 4; ++nf) {
          const int kvb = kv0 + nf * 16 + lhi * 4;
#pragma unroll
          for (int r = 0; r < 4; ++r)
            if (kvb + r > q) s[mf][nf][r] = -1e30f;
        }
      // row max: in-register over nf,r then 2 shfl over lhi
      f32x4 t4 = s[mf][0];
#pragma unroll
      for (int nf = 1; nf < 4; ++nf)
#pragma unroll
        for (int r = 0; r < 4; ++r) t4[r] = fmaxf(t4[r], s[mf][nf][r]);
      float pm = fmaxf(fmaxf(t4[0], t4[1]), fmaxf(t4[2], t4[3]));
      pm = fmaxf(pm, __shfl_xor(pm, 16, 64));
      pm = fmaxf(pm, __shfl_xor(pm, 32, 64));
      // defer-max: only rescale when the running max grew materially
      if (__any(pm > mrun[mf] + 8.0f)) {
        const float mnew = fmaxf(mrun[mf], pm);
        const float sc = EXP2(mrun[mf] - mnew);
        mrun[mf] = mnew;
        lrun[mf] *= sc;
#pragma unroll
        for (int nf = 0; nf < 4; ++nf)
#pragma unroll
          for (int r = 0; r < 4; ++r) o[mf][nf][r] *= sc;
      }
      float rs = 0.0f;
#pragma unroll
      for (int nf = 0; nf < 4; ++nf)
#pragma unroll
        for (int r = 0; r < 4; ++r) {
          float p = EXP2(s[mf][nf][r] - mrun[mf]);
          s[mf][nf][r] = p;
          rs += p;
        }
      rs += __shfl_xor(rs, 16, 64);
      rs += __shfl_xor(rs, 32, 64);
      lrun[mf] += rs;

      // P -> LDS: cvt_pk pairs + one ds_write_b64 per nf
      char* base = Pw + (mf * 16 + l15) * 128;
#pragma unroll
      for (int nf = 0; nf < 4; ++nf) {
        unsigned lo = cvtpk(s[mf][nf][0], s[mf][nf][1]);
        unsigned hi = cvtpk(s[mf][nf][2], s[mf][nf][3]);
        *(unsigned long long*)(base + ((nf * 32 + lhi * 8) ^ swz)) =
            (unsigned long long)lo | ((unsigned long long)hi << 32);
      }
    }

    // swapped PV: o[mf][nf][r] = O[q = r0+mf*16+l15][dh = nf*16+lhi*4+r]
    __builtin_amdgcn_s_setprio(1);
#pragma unroll
    for (int mf = 0; mf < 2; ++mf) {
      const char* base = Pw + (mf * 16 + l15) * 128;
      short8 ap0 = *(const short8*)(base + ((lhi * 16) ^ swz));
      short8 ap1 = *(const short8*)(base + ((64 + lhi * 16) ^ swz));
#pragma unroll
      for (int nf = 0; nf < 4; ++nf) {
        o[mf][nf] = __builtin_amdgcn_mfma_f32_16x16x32_bf16(bv[nf][0], ap0, o[mf][nf], 0, 0, 0);
        o[mf][nf] = __builtin_amdgcn_mfma_f32_16x16x32_bf16(bv[nf][1], ap1, o[mf][nf], 0, 0, 0);
      }
    }
    __builtin_amdgcn_s_setprio(0);
  }

  // merge the two kv-half partials (flash combine), then store.
  // Barrier REQUIRED before the dump: Ob overlays Pbuf.
  __syncthreads();
  if (wid == 1) {
#pragma unroll
    for (int mf = 0; mf < 2; ++mf) {
      const int row = mf * 16 + l15;
      if (lhi == 0) { Mb[row] = mrun[mf]; Lb[row] = lrun[mf]; }
#pragma unroll
      for (int nf = 0; nf < 4; ++nf)
        *(f32x4*)&Ob[row][nf * 16 + lhi * 4] = o[mf][nf];
    }
  }
  __syncthreads();
  if (wid == 0) {
    const int b_ = bh >> 4, h = bh & 15;
#pragma unroll
    for (int mf = 0; mf < 2; ++mf) {
      const int row = mf * 16 + l15;
      const float m1 = Mb[row], l1 = Lb[row];
      const float mt = fmaxf(mrun[mf], m1);
      const float sc0 = EXP2(mrun[mf] - mt);
      const float sc1 = EXP2(m1 - mt);
      const float inv = 1.0f / (lrun[mf] * sc0 + l1 * sc1);
      __hip_bfloat16* dst = att + ((size_t)(b_ * LL + r0 + row)) * DD + h * DHH;
#pragma unroll
      for (int nf = 0; nf < 4; ++nf) {
        f32x4 ov = *(const f32x4*)&Ob[row][nf * 16 + lhi * 4];
        float f0 = (o[mf][nf][0] * sc0 + ov[0] * sc1) * inv;
        float f1 = (o[mf][nf][1] * sc0 + ov[1] * sc1) * inv;
        float f2 = (o[mf][nf][2] * sc0 + ov[2] * sc1) * inv;
        float f3 = (o[mf][nf][3] * sc0 + ov[3] * sc1) * inv;
        uint2v pk;
        pk[0] = cvtpk(f0, f1);
        pk[1] = cvtpk(f2, f3);
        *(uint2v*)(dst + nf * 16 + lhi * 4) = pk;
      }
    }
  }
}

extern "C" void kernel_launch(void* const* d_in, const int* in_sizes, int n_in,
                              void* d_out, int out_size, void* d_ws, size_t ws_size,
                              hipStream_t stream) {
  const float* x     = (const float*)d_in[0];
  const float* w_in  = (const float*)d_in[1];
  const float* b_in  = (const float*)d_in[2];
  const float* w_out = (const float*)d_in[3];
  const int* mask    = (const int*)d_in[4];
  float* out = (float*)d_out;

  char* ws = (char*)d_ws;
  const size_t MiB = 1024u * 1024u;
  __hip_bfloat16* xb    = (__hip_bfloat16*)(ws);             // 8 MiB
  __hip_bfloat16* w_inb = (__hip_bfloat16*)(ws + 8 * MiB);   // 6 MiB
  __hip_bfloat16* w_outb= (__hip_bfloat16*)(ws + 14 * MiB);  // 2 MiB
  __hip_bfloat16* Qb    = (__hip_bfloat16*)(ws + 16 * MiB);  // 8 MiB
  __hip_bfloat16* Kb    = (__hip_bfloat16*)(ws + 24 * MiB);  // 8 MiB
  __hip_bfloat16* Vtb   = (__hip_bfloat16*)(ws + 32 * MiB);  // 8 MiB (transposed)
  __hip_bfloat16* att   = (__hip_bfloat16*)(ws + 40 * MiB);  // 8 MiB

  // fused conversions: (524288+393216+131072)/256 = 4096 blocks
  cvt_all<<<dim3(4096), dim3(256), 0, stream>>>(x, w_in, w_out, xb, w_inb, w_outb);

  gemm_bt<true><<<dim3(32 * 24), dim3(256), 0, stream>>>(
      xb, w_inb, b_in, Qb, Kb, Vtb, nullptr, 3072, 24);
  attn_fwd<<<dim3(2048), dim3(128), 0, stream>>>(Qb, Kb, Vtb, att, mask);
  gemm_bt<false><<<dim3(32 * 8), dim3(256), 0, stream>>>(
      att, w_outb, nullptr, nullptr, nullptr, nullptr, out, 1024, 8);
}

// Round 25
// 128.775 us; speedup vs baseline: 1.2286x; 1.0083x over previous
//
#include <hip/hip_runtime.h>
#include <hip/hip_bf16.h>

typedef __attribute__((ext_vector_type(8))) short short8;
typedef __attribute__((ext_vector_type(4))) short short4v;
typedef __attribute__((ext_vector_type(4))) float f32x4;
typedef __attribute__((ext_vector_type(2))) unsigned uint2v;

#define BB 2
#define LL 2048
#define DD 1024
#define HH 16
#define DHH 64
#define KK 1024
// 0.125 (1/sqrt(64)) * log2(e): folded into Q at the QKV epilogue
#define SCL 0.18033688011112042f
#define EXP2(x) __builtin_amdgcn_exp2f(x)

__device__ __forceinline__ void gload_lds16(const void* g, void* l) {
  __builtin_amdgcn_global_load_lds((const __attribute__((address_space(1))) void*)g,
                                   (__attribute__((address_space(3))) void*)l,
                                   16, 0, 0);
}

__device__ __forceinline__ unsigned short f2b(float x) {
  __hip_bfloat16 h = __float2bfloat16(x);
  return *reinterpret_cast<unsigned short*>(&h);
}

// HW packed f32->bf16 (RNE): one VALU inst vs ~5 for __float2bfloat16.
__device__ __forceinline__ unsigned cvtpk(float lo, float hi) {
  unsigned r;
  asm("v_cvt_pk_bf16_f32 %0, %1, %2" : "=v"(r) : "v"(lo), "v"(hi));
  return r;
}

// fused fp32 -> bf16 convert for x, w_in, w_out (one launch)
#define NX8  ((BB * LL * DD) / 8)      // 524288
#define NWI8 ((3 * DD * DD) / 8)       // 393216
#define NWO8 ((DD * DD) / 8)           // 131072
__global__ void cvt_all(const float* __restrict__ x,
                        const float* __restrict__ w_in,
                        const float* __restrict__ w_out,
                        __hip_bfloat16* __restrict__ xb,
                        __hip_bfloat16* __restrict__ w_inb,
                        __hip_bfloat16* __restrict__ w_outb) {
  int i = blockIdx.x * blockDim.x + threadIdx.x;
  const float* src;
  __hip_bfloat16* dst;
  int j;
  if (i < NX8)              { src = x;     dst = xb;     j = i; }
  else if (i < NX8 + NWI8)  { src = w_in;  dst = w_inb;  j = i - NX8; }
  else                      { src = w_out; dst = w_outb; j = i - NX8 - NWI8; }
  const f32x4 a = ((const f32x4*)src)[j * 2];
  const f32x4 b = ((const f32x4*)src)[j * 2 + 1];
  short8 o;
#pragma unroll
  for (int k = 0; k < 4; ++k) o[k] = (short)f2b(a[k]);
#pragma unroll
  for (int k = 0; k < 4; ++k) o[4 + k] = (short)f2b(b[k]);
  ((short8*)dst)[j] = o;
}

// C = A @ B^T (+bias). A: MxK bf16 row-major, B: NxK bf16 row-major. K=1024.
// BK=64 (r19-validated: 16 K-steps, 32 MFMA per barrier-pair).
template<bool QKV>
__global__ void gemm_bt(const __hip_bfloat16* __restrict__ A,
                        const __hip_bfloat16* __restrict__ Bm,
                        const float* __restrict__ bias,
                        __hip_bfloat16* __restrict__ Cq,
                        __hip_bfloat16* __restrict__ Ck,
                        __hip_bfloat16* __restrict__ Cv,
                        float* __restrict__ Cd,
                        int N, int nbn) {
  __shared__ __align__(16) char As[16384];   // [128 rows][128B], swizzled
  __shared__ __align__(16) char Bs[16384];
  const int tid = threadIdx.x;
  const int lane = tid & 63, wid = tid >> 6;
  const int l15 = lane & 15, lhi = lane >> 4;
  const int wm = wid >> 1, wn = wid & 1;
  const int bn = blockIdx.x % nbn, bm = blockIdx.x / nbn;
  const int m0 = bm * 128, n0 = bn * 128;

  f32x4 acc[4][4] = {};

  for (int kt = 0; kt < KK / 64; ++kt) {
    const int k0 = kt * 64;
    __syncthreads();
    // stage A+B tiles: chunk c: row = c>>3, byte = ((c&7)*16) ^ ((row&7)<<4)
#pragma unroll
    for (int j = 0; j < 4; ++j) {
      int c = wid * 256 + j * 64 + lane;
      int row = c >> 3;
      int ab = ((c & 7) * 16) ^ ((row & 7) << 4);
      gload_lds16(A + (size_t)(m0 + row) * KK + k0 + (ab >> 1),
                  As + wid * 4096 + j * 1024);
    }
#pragma unroll
    for (int j = 0; j < 4; ++j) {
      int c = wid * 256 + j * 64 + lane;
      int row = c >> 3;
      int ab = ((c & 7) * 16) ^ ((row & 7) << 4);
      gload_lds16(Bm + (size_t)(n0 + row) * KK + k0 + (ab >> 1),
                  Bs + wid * 4096 + j * 1024);
    }
    __syncthreads();

#pragma unroll
    for (int kk = 0; kk < 2; ++kk) {
      short8 af[4], bf[4];
#pragma unroll
      for (int mf = 0; mf < 4; ++mf) {
        int row = wm * 64 + mf * 16 + l15;
        int byt = (kk * 64 + lhi * 16) ^ ((row & 7) << 4);
        af[mf] = *(const short8*)(As + row * 128 + byt);
      }
#pragma unroll
      for (int nf = 0; nf < 4; ++nf) {
        int row = wn * 64 + nf * 16 + l15;
        int byt = (kk * 64 + lhi * 16) ^ ((row & 7) << 4);
        bf[nf] = *(const short8*)(Bs + row * 128 + byt);
      }
#pragma unroll
      for (int mf = 0; mf < 4; ++mf)
#pragma unroll
        for (int nf = 0; nf < 4; ++nf)
          acc[mf][nf] = __builtin_amdgcn_mfma_f32_16x16x32_bf16(af[mf], bf[nf],
                                                                acc[mf][nf], 0, 0, 0);
    }
  }

  // epilogue: C/D layout col=lane&15, row=(lane>>4)*4+reg
#pragma unroll
  for (int mf = 0; mf < 4; ++mf) {
#pragma unroll
    for (int nf = 0; nf < 4; ++nf) {
      const int n = n0 + wn * 64 + nf * 16 + l15;
      if constexpr (QKV) {
        const int sect = n >> 10;          // 0=q 1=k 2=v
        const int nn = n & 1023;
        const int h = nn >> 6, dh = nn & 63;
        const float bv = bias[n];
        const int m_base = m0 + wm * 64 + mf * 16 + lhi * 4;   // +r, same 2k page
        const int b = m_base >> 11, ml = m_base & 2047;
        if (sect == 2) {
          // V transposed: [b*H+h][dh][l]; 4 r-values are l-contiguous -> 8B store
          short4v v;
#pragma unroll
          for (int r = 0; r < 4; ++r) v[r] = (short)f2b(acc[mf][nf][r] + bv);
          *(short4v*)&Cv[(((size_t)(b * HH + h)) * DHH + dh) * LL + ml] = v;
        } else {
          __hip_bfloat16* dst = (sect == 0) ? Cq : Ck;
          const float scl = (sect == 0) ? SCL : 1.0f;   // fold softmax scale into Q
#pragma unroll
          for (int r = 0; r < 4; ++r)
            dst[(((size_t)(b * HH + h)) * LL + ml + r) * DHH + dh] =
                __float2bfloat16((acc[mf][nf][r] + bv) * scl);
        }
      } else {
#pragma unroll
        for (int r = 0; r < 4; ++r) {
          const int m = m0 + wm * 64 + mf * 16 + lhi * 4 + r;
          Cd[(size_t)m * N + n] = acc[mf][nf][r];
        }
      }
    }
  }
}

// Flash attention, swapped-operand form (r18/r19 body) with INTERLEAVED
// kv partition: wave0 takes even tiles, wave1 odd tiles (any disjoint
// partition is valid for the flash merge). Both waves touch adjacent
// tiles near-simultaneously -> shared L1/L2 temporal locality, vs the
// disjoint-range split where the two streams never overlapped.
// strip = 63-(bid>>5) descending, head pinned to XCD via bid&31 (static
// mapping preserves L2 locality; r23's dynamic queue broke it, 10x FETCH).
__global__ __launch_bounds__(128)
__attribute__((amdgpu_waves_per_eu(1, 4)))
void attn_fwd(
    const __hip_bfloat16* __restrict__ Q,
    const __hip_bfloat16* __restrict__ K,
    const __hip_bfloat16* __restrict__ VT,
    __hip_bfloat16* __restrict__ att,
    const int* __restrict__ maskp) {
  __shared__ __align__(16) char shm[8960];
  // loop phase:  Pbuf = shm[0..8192), per-wave [row32][128B], off^=((l15&7)<<4)
  // merge phase: Ob = shm[0..8704) as float[32][68]; Mb@8704; Lb@8832
  char* Pw = shm + (threadIdx.x >> 6) * 4096;
  float (*Ob)[68] = (float(*)[68])shm;
  float* Mb = (float*)(shm + 8704);
  float* Lb = (float*)(shm + 8832);
  const int tid = threadIdx.x;
  const int lane = tid & 63, wid = tid >> 6;
  const int l15 = lane & 15, lhi = lane >> 4;
  const int bid = blockIdx.x;
  const int strip = 63 - (bid >> 5);        // heavy strips dispatched first
  const int bh = bid & 31;                  // head pinned to one XCD's L2
  const int causal = *maskp;
  const int r0 = strip * 32;
  const __hip_bfloat16* Qg = Q + (size_t)bh * LL * DHH;
  const __hip_bfloat16* Kg = K + (size_t)bh * LL * DHH;
  const __hip_bfloat16* VTg = VT + (size_t)bh * DHH * LL;
  const int swz = (l15 & 7) << 4;

  // Q fragments (B-operand; pre-scaled by SCL in the QKV epilogue)
  short8 aq[2][2];
#pragma unroll
  for (int mf = 0; mf < 2; ++mf)
#pragma unroll
    for (int ks = 0; ks < 2; ++ks)
      aq[mf][ks] = *(const short8*)(Qg + (size_t)(r0 + mf * 16 + l15) * DHH +
                                    ks * 32 + lhi * 8);

  f32x4 o[2][4] = {};
  float mrun[2] = {-1e30f, -1e30f};
  float lrun[2] = {0.0f, 0.0f};

  const int nt = causal ? ((r0 + 31) >> 6) + 1 : (LL / 64);
  const int t0 = wid;                       // wave0: even tiles, wave1: odd

  // stepped base pointers (advance TWO tiles per iteration)
  const __hip_bfloat16* kb0 = Kg + (size_t)(t0 * 64 + l15) * DHH + lhi * 8;        // nf 0,1
  const __hip_bfloat16* kb2 = Kg + (size_t)(t0 * 64 + 32 + l15) * DHH + lhi * 8;   // nf 2,3
  const __hip_bfloat16* vp0 = VTg + (size_t)(l15) * LL + t0 * 64 + lhi * 8;
  const __hip_bfloat16* vp1 = VTg + (size_t)(16 + l15) * LL + t0 * 64 + lhi * 8;
  const __hip_bfloat16* vp2 = VTg + (size_t)(32 + l15) * LL + t0 * 64 + lhi * 8;
  const __hip_bfloat16* vp3 = VTg + (size_t)(48 + l15) * LL + t0 * 64 + lhi * 8;

  for (int t = t0; t < nt; t += 2) {
    const int kv0 = t * 64;
    f32x4 s[2][4] = {};

    // K half 0 first (oldest in vmcnt queue), then ALL V loads: QK^T waits
    // only for K; V stays in flight under softmax.
    short8 kah[4];
    kah[0] = *(const short8*)(kb0);
    kah[1] = *(const short8*)(kb0 + 1024);
    kah[2] = *(const short8*)(kb2);
    kah[3] = *(const short8*)(kb2 + 1024);
    short8 bv[4][2];
    bv[0][0] = *(const short8*)(vp0);  bv[0][1] = *(const short8*)(vp0 + 32);
    bv[1][0] = *(const short8*)(vp1);  bv[1][1] = *(const short8*)(vp1 + 32);
    bv[2][0] = *(const short8*)(vp2);  bv[2][1] = *(const short8*)(vp2 + 32);
    bv[3][0] = *(const short8*)(vp3);  bv[3][1] = *(const short8*)(vp3 + 32);

    // swapped QK^T: s[mf][nf][r] = S[q = r0+mf*16+l15][kv = kv0+nf*16+lhi*4+r]
    __builtin_amdgcn_s_setprio(1);
#pragma unroll
    for (int nf = 0; nf < 4; ++nf) {
      s[0][nf] = __builtin_amdgcn_mfma_f32_16x16x32_bf16(kah[nf], aq[0][0], s[0][nf], 0, 0, 0);
      s[1][nf] = __builtin_amdgcn_mfma_f32_16x16x32_bf16(kah[nf], aq[1][0], s[1][nf], 0, 0, 0);
    }
    __builtin_amdgcn_s_setprio(0);
    // K half 1
    kah[0] = *(const short8*)(kb0 + 32);
    kah[1] = *(const short8*)(kb0 + 1024 + 32);
    kah[2] = *(const short8*)(kb2 + 32);
    kah[3] = *(const short8*)(kb2 + 1024 + 32);
    __builtin_amdgcn_s_setprio(1);
#pragma unroll
    for (int nf = 0; nf < 4; ++nf) {
      s[0][nf] = __builtin_amdgcn_mfma_f32_16x16x32_bf16(kah[nf], aq[0][1], s[0][nf], 0, 0, 0);
      s[1][nf] = __builtin_amdgcn_mfma_f32_16x16x32_bf16(kah[nf], aq[1][1], s[1][nf], 0, 0, 0);
    }
    __builtin_amdgcn_s_setprio(0);

    // advance base pointers by two tiles
    kb0 += 8192; kb2 += 8192;
    vp0 += 128; vp1 += 128; vp2 += 128; vp3 += 128;

    const bool needmask = causal && (kv0 + 63 > r0);
#pragma unroll
    for (int mf = 0; mf < 2; ++mf) {
      const int q = r0 + mf * 16 + l15;
      // causal mask only (scale already folded into Q)
      if (needmask)
#pragma unroll
        for (int nf = 0; nf < 4; ++nf) {
          const int kvb = kv0 + nf * 16 + lhi * 4;
#pragma unroll
          for (int r = 0; r < 4; ++r)
            if (kvb + r > q) s[mf][nf][r] = -1e30f;
        }
      // row max: in-register over nf,r then 2 shfl over lhi
      f32x4 t4 = s[mf][0];
#pragma unroll
      for (int nf = 1; nf < 4; ++nf)
#pragma unroll
        for (int r = 0; r < 4; ++r) t4[r] = fmaxf(t4[r], s[mf][nf][r]);
      float pm = fmaxf(fmaxf(t4[0], t4[1]), fmaxf(t4[2], t4[3]));
      pm = fmaxf(pm, __shfl_xor(pm, 16, 64));
      pm = fmaxf(pm, __shfl_xor(pm, 32, 64));
      // defer-max: only rescale when the running max grew materially
      if (__any(pm > mrun[mf] + 8.0f)) {
        const float mnew = fmaxf(mrun[mf], pm);
        const float sc = EXP2(mrun[mf] - mnew);
        mrun[mf] = mnew;
        lrun[mf] *= sc;
#pragma unroll
        for (int nf = 0; nf < 4; ++nf)
#pragma unroll
          for (int r = 0; r < 4; ++r) o[mf][nf][r] *= sc;
      }
      float rs = 0.0f;
#pragma unroll
      for (int nf = 0; nf < 4; ++nf)
#pragma unroll
        for (int r = 0; r < 4; ++r) {
          float p = EXP2(s[mf][nf][r] - mrun[mf]);
          s[mf][nf][r] = p;
          rs += p;
        }
      rs += __shfl_xor(rs, 16, 64);
      rs += __shfl_xor(rs, 32, 64);
      lrun[mf] += rs;

      // P -> LDS: cvt_pk pairs + one ds_write_b64 per nf
      char* base = Pw + (mf * 16 + l15) * 128;
#pragma unroll
      for (int nf = 0; nf < 4; ++nf) {
        unsigned lo = cvtpk(s[mf][nf][0], s[mf][nf][1]);
        unsigned hi = cvtpk(s[mf][nf][2], s[mf][nf][3]);
        *(unsigned long long*)(base + ((nf * 32 + lhi * 8) ^ swz)) =
            (unsigned long long)lo | ((unsigned long long)hi << 32);
      }
    }

    // swapped PV: o[mf][nf][r] = O[q = r0+mf*16+l15][dh = nf*16+lhi*4+r]
    __builtin_amdgcn_s_setprio(1);
#pragma unroll
    for (int mf = 0; mf < 2; ++mf) {
      const char* base = Pw + (mf * 16 + l15) * 128;
      short8 ap0 = *(const short8*)(base + ((lhi * 16) ^ swz));
      short8 ap1 = *(const short8*)(base + ((64 + lhi * 16) ^ swz));
#pragma unroll
      for (int nf = 0; nf < 4; ++nf) {
        o[mf][nf] = __builtin_amdgcn_mfma_f32_16x16x32_bf16(bv[nf][0], ap0, o[mf][nf], 0, 0, 0);
        o[mf][nf] = __builtin_amdgcn_mfma_f32_16x16x32_bf16(bv[nf][1], ap1, o[mf][nf], 0, 0, 0);
      }
    }
    __builtin_amdgcn_s_setprio(0);
  }

  // merge the two parity partials (flash combine), then store.
  // Barrier REQUIRED before the dump: Ob overlays Pbuf.
  __syncthreads();
  if (wid == 1) {
#pragma unroll
    for (int mf = 0; mf < 2; ++mf) {
      const int row = mf * 16 + l15;
      if (lhi == 0) { Mb[row] = mrun[mf]; Lb[row] = lrun[mf]; }
#pragma unroll
      for (int nf = 0; nf < 4; ++nf)
        *(f32x4*)&Ob[row][nf * 16 + lhi * 4] = o[mf][nf];
    }
  }
  __syncthreads();
  if (wid == 0) {
    const int b_ = bh >> 4, h = bh & 15;
#pragma unroll
    for (int mf = 0; mf < 2; ++mf) {
      const int row = mf * 16 + l15;
      const float m1 = Mb[row], l1 = Lb[row];
      const float mt = fmaxf(mrun[mf], m1);
      const float sc0 = EXP2(mrun[mf] - mt);
      const float sc1 = EXP2(m1 - mt);
      const float inv = 1.0f / (lrun[mf] * sc0 + l1 * sc1);
      __hip_bfloat16* dst = att + ((size_t)(b_ * LL + r0 + row)) * DD + h * DHH;
#pragma unroll
      for (int nf = 0; nf < 4; ++nf) {
        f32x4 ov = *(const f32x4*)&Ob[row][nf * 16 + lhi * 4];
        float f0 = (o[mf][nf][0] * sc0 + ov[0] * sc1) * inv;
        float f1 = (o[mf][nf][1] * sc0 + ov[1] * sc1) * inv;
        float f2 = (o[mf][nf][2] * sc0 + ov[2] * sc1) * inv;
        float f3 = (o[mf][nf][3] * sc0 + ov[3] * sc1) * inv;
        uint2v pk;
        pk[0] = cvtpk(f0, f1);
        pk[1] = cvtpk(f2, f3);
        *(uint2v*)(dst + nf * 16 + lhi * 4) = pk;
      }
    }
  }
}

extern "C" void kernel_launch(void* const* d_in, const int* in_sizes, int n_in,
                              void* d_out, int out_size, void* d_ws, size_t ws_size,
                              hipStream_t stream) {
  const float* x     = (const float*)d_in[0];
  const float* w_in  = (const float*)d_in[1];
  const float* b_in  = (const float*)d_in[2];
  const float* w_out = (const float*)d_in[3];
  const int* mask    = (const int*)d_in[4];
  float* out = (float*)d_out;

  char* ws = (char*)d_ws;
  const size_t MiB = 1024u * 1024u;
  __hip_bfloat16* xb    = (__hip_bfloat16*)(ws);             // 8 MiB
  __hip_bfloat16* w_inb = (__hip_bfloat16*)(ws + 8 * MiB);   // 6 MiB
  __hip_bfloat16* w_outb= (__hip_bfloat16*)(ws + 14 * MiB);  // 2 MiB
  __hip_bfloat16* Qb    = (__hip_bfloat16*)(ws + 16 * MiB);  // 8 MiB
  __hip_bfloat16* Kb    = (__hip_bfloat16*)(ws + 24 * MiB);  // 8 MiB
  __hip_bfloat16* Vtb   = (__hip_bfloat16*)(ws + 32 * MiB);  // 8 MiB (transposed)
  __hip_bfloat16* att   = (__hip_bfloat16*)(ws + 40 * MiB);  // 8 MiB

  // fused conversions: (524288+393216+131072)/256 = 4096 blocks
  cvt_all<<<dim3(4096), dim3(256), 0, stream>>>(x, w_in, w_out, xb, w_inb, w_outb);

  gemm_bt<true><<<dim3(32 * 24), dim3(256), 0, stream>>>(
      xb, w_inb, b_in, Qb, Kb, Vtb, nullptr, 3072, 24);
  attn_fwd<<<dim3(2048), dim3(128), 0, stream>>>(Qb, Kb, Vtb, att, mask);
  gemm_bt<false><<<dim3(32 * 8), dim3(256), 0, stream>>>(
      att, w_outb, nullptr, nullptr, nullptr, nullptr, out, 1024, 8);
}